// Round 1
// 601.854 us; speedup vs baseline: 1.0491x; 1.0491x over previous
//
#include <hip/hip_runtime.h>
#include <hip/hip_bf16.h>
#include <cstdint>
#include <cstddef>

// ---------- types / helpers ----------
typedef __bf16 bf16x8 __attribute__((ext_vector_type(8)));
typedef float  f32x4  __attribute__((ext_vector_type(4)));
using u16 = unsigned short;
using u32 = unsigned int;

__device__ __forceinline__ float b2f(u16 u) {
  u32 v = ((u32)u) << 16;
  float f; __builtin_memcpy(&f, &v, 4); return f;
}
__device__ __forceinline__ u16 f2b(float f) {
  u32 v; __builtin_memcpy(&v, &f, 4);
  u32 r = v + 0x7fffu + ((v >> 16) & 1u);   // RTNE
  return (u16)(r >> 16);
}
__device__ __forceinline__ float silu(float x) {
  return x / (1.f + __expf(-x));
}
__device__ __forceinline__ f32x4 zero4() { f32x4 v = {0.f,0.f,0.f,0.f}; return v; }

typedef __attribute__((address_space(1))) const void* gas_ptr;
typedef __attribute__((address_space(3))) void*       las_ptr;
__device__ __forceinline__ void async_copy16(const void* g, void* l) {
  __builtin_amdgcn_global_load_lds((gas_ptr)g, (las_ptr)l, 16, 0, 0);
}

// ---------- weight convert: fp32 -> bf16, 5 segments ----------
__global__ __launch_bounds__(256) void cvt_kernel(
    const float* __restrict__ wqkv, const float* __restrict__ wu,
    const float* __restrict__ w0,   const float* __restrict__ w1,
    const float* __restrict__ w3,
    u16* bqkv, u16* bu, u16* b0, u16* b1, u16* b3)
{
  const int blk = blockIdx.x;
  const float* src; u16* dst; int base;
  if      (blk < 3072) { src = wqkv; dst = bqkv; base = blk; }
  else if (blk < 4096) { src = wu;   dst = bu;   base = blk - 3072; }
  else if (blk < 5120) { src = w0;   dst = b0;   base = blk - 4096; }
  else if (blk < 7168) { src = w1;   dst = b1;   base = blk - 5120; }
  else                 { src = w3;   dst = b3;   base = blk - 7168; }
  const size_t i = (size_t)base * 1024 + threadIdx.x * 4;
  float4 v = *(const float4*)(src + i);
  uint2 o;
  o.x = (u32)f2b(v.x) | ((u32)f2b(v.y) << 16);
  o.y = (u32)f2b(v.z) | ((u32)f2b(v.w) << 16);
  *(uint2*)(dst + i) = o;
}

// ---------- GEMM 128x128: C[M,N] = A[M,K] * B[N,K]^T  (bf16 in, fp32 acc) ----------
// Used only for the wide qkv GEMM (N=3072, grid 24x32 = 3 blocks/CU).
template<int EPI>
__global__ __launch_bounds__(256) void gemm_bt(
    const u16* __restrict__ A, const u16* __restrict__ Bw,
    const float* __restrict__ res, void* __restrict__ Cp,
    int M, int N, int K)
{
  __shared__ u16 sA[128 * 32];
  __shared__ u16 sB[128 * 32];

  const int t    = threadIdx.x;
  const int wave = t >> 6, lane = t & 63;
  const int quad = lane >> 4, l16 = lane & 15;
  const int wm = wave >> 1, wn = wave & 1;

  // XCD-aware swizzle (grid size is a multiple of 8 -> bijective)
  const int nwg = gridDim.x * gridDim.y;
  const int bid = blockIdx.y * gridDim.x + blockIdx.x;
  const int v   = (bid & 7) * (nwg >> 3) + (bid >> 3);
  const int bx  = v % gridDim.x, by = v / gridDim.x;
  const int m0 = by * 128, n0 = bx * 128;

  const int arow = t >> 2, achunk = t & 3;
  const u16* gA = A  + (size_t)(m0 + arow) * K + achunk * 8;
  const u16* gB = Bw + (size_t)(n0 + arow) * K + achunk * 8;
  u16* lA = sA + t * 8;
  u16* lB = sB + t * 8;

  f32x4 acc[4][4];
#pragma unroll
  for (int i = 0; i < 4; i++)
#pragma unroll
    for (int j = 0; j < 4; j++) acc[i][j] = zero4();

  for (int kb = 0; kb < K; kb += 32) {
    async_copy16(gA + kb,                 lA);
    async_copy16(gA + kb + (size_t)64*K,  lA + 2048);
    async_copy16(gB + kb,                 lB);
    async_copy16(gB + kb + (size_t)64*K,  lB + 2048);
    __syncthreads();

    bf16x8 af[4], bfr[4];
#pragma unroll
    for (int mi = 0; mi < 4; mi++)
      af[mi]  = *(const bf16x8*)(sA + (wm*64 + mi*16 + l16)*32 + quad*8);
#pragma unroll
    for (int ni = 0; ni < 4; ni++)
      bfr[ni] = *(const bf16x8*)(sB + (wn*64 + ni*16 + l16)*32 + quad*8);
#pragma unroll
    for (int mi = 0; mi < 4; mi++)
#pragma unroll
      for (int ni = 0; ni < 4; ni++)
        acc[mi][ni] = __builtin_amdgcn_mfma_f32_16x16x32_bf16(af[mi], bfr[ni], acc[mi][ni], 0, 0, 0);
    __syncthreads();
  }

#pragma unroll
  for (int mi = 0; mi < 4; mi++) {
#pragma unroll
    for (int ni = 0; ni < 4; ni++) {
#pragma unroll
      for (int r = 0; r < 4; r++) {
        const int row = m0 + wm*64 + mi*16 + quad*4 + r;
        const int col = n0 + wn*64 + ni*16 + l16;
        const size_t idx = (size_t)row * N + col;
        float vv = acc[mi][ni][r];
        if constexpr (EPI == 0) {
          ((u16*)Cp)[idx] = f2b(vv);
        } else if constexpr (EPI == 1) {
          ((u16*)Cp)[idx] = f2b(silu(vv));
        } else {
          ((float*)Cp)[idx] = vv + res[idx];
        }
      }
    }
  }
}

// ---------- GEMM 128x64: for N=1024 GEMMs -> grid (16,32)=512 blocks = 2/CU ----------
// EPI: 1 = silu -> bf16; 2 = + f32 residual -> store f32; 3 = same as 2
template<int EPI>
__global__ __launch_bounds__(256) void gemm64_bt(
    const u16* __restrict__ A, const u16* __restrict__ Bw,
    const float* __restrict__ res, void* __restrict__ Cp,
    int M, int N, int K)
{
  __shared__ u16 sA[128 * 32];
  __shared__ u16 sB[ 64 * 32];

  const int t    = threadIdx.x;
  const int wave = t >> 6, lane = t & 63;
  const int quad = lane >> 4, l16 = lane & 15;
  const int wm = wave >> 1, wn = wave & 1;

  // XCD-aware swizzle (nwg = 512)
  const int nwg = gridDim.x * gridDim.y;
  const int bid = blockIdx.y * gridDim.x + blockIdx.x;
  const int v   = (bid & 7) * (nwg >> 3) + (bid >> 3);
  const int bx  = v & (gridDim.x - 1), by = v / gridDim.x;  // gridDim.x = 16 (pow2)
  const int m0 = by * 128, n0 = bx * 64;

  const int arow = t >> 2, achunk = t & 3;
  const u16* gA = A  + (size_t)(m0 + arow) * K + achunk * 8;
  const u16* gB = Bw + (size_t)(n0 + arow) * K + achunk * 8;   // 64 B rows
  u16* lA = sA + t * 8;
  u16* lB = sB + t * 8;

  f32x4 acc[4][2];
#pragma unroll
  for (int i = 0; i < 4; i++) { acc[i][0] = zero4(); acc[i][1] = zero4(); }

  for (int kb = 0; kb < K; kb += 32) {
    async_copy16(gA + kb,                 lA);
    async_copy16(gA + kb + (size_t)64*K,  lA + 2048);
    async_copy16(gB + kb,                 lB);
    __syncthreads();

    bf16x8 af[4], bfr[2];
#pragma unroll
    for (int mi = 0; mi < 4; mi++)
      af[mi]  = *(const bf16x8*)(sA + (wm*64 + mi*16 + l16)*32 + quad*8);
#pragma unroll
    for (int ni = 0; ni < 2; ni++)
      bfr[ni] = *(const bf16x8*)(sB + (wn*32 + ni*16 + l16)*32 + quad*8);
#pragma unroll
    for (int mi = 0; mi < 4; mi++)
#pragma unroll
      for (int ni = 0; ni < 2; ni++)
        acc[mi][ni] = __builtin_amdgcn_mfma_f32_16x16x32_bf16(af[mi], bfr[ni], acc[mi][ni], 0, 0, 0);
    __syncthreads();
  }

#pragma unroll
  for (int mi = 0; mi < 4; mi++) {
#pragma unroll
    for (int ni = 0; ni < 2; ni++) {
#pragma unroll
      for (int r = 0; r < 4; r++) {
        const int row = m0 + wm*64 + mi*16 + quad*4 + r;
        const int col = n0 + wn*32 + ni*16 + l16;
        const size_t idx = (size_t)row * N + col;
        float vv = acc[mi][ni][r];
        if constexpr (EPI == 1) {
          ((u16*)Cp)[idx] = f2b(silu(vv));
        } else {
          ((float*)Cp)[idx] = vv + res[idx];
        }
      }
    }
  }
}

// ---------- fused w1 GEMM + GLU: hid[r, c] = silu(A@w1[c]) * (A@w1[c+1024]) ----------
// BM=128, per-block output cols n0..n0+63; computes both x1 and x2 tiles.
__global__ __launch_bounds__(256) void gemm_glu(
    const u16* __restrict__ A, const u16* __restrict__ Bw,
    u16* __restrict__ hid, int K)
{
  __shared__ u16 sA [128 * 32];
  __shared__ u16 sB1[ 64 * 32];
  __shared__ u16 sB2[ 64 * 32];

  const int t    = threadIdx.x;
  const int wave = t >> 6, lane = t & 63;
  const int quad = lane >> 4, l16 = lane & 15;
  const int wm = wave >> 1, wn = wave & 1;

  const int nwg = gridDim.x * gridDim.y;
  const int bid = blockIdx.y * gridDim.x + blockIdx.x;
  const int v   = (bid & 7) * (nwg >> 3) + (bid >> 3);
  const int bx  = v & (gridDim.x - 1), by = v / gridDim.x;
  const int m0 = by * 128, n0 = bx * 64;

  const int arow = t >> 2, achunk = t & 3;
  const u16* gA  = A  + (size_t)(m0 + arow) * K + achunk * 8;
  const u16* gB1 = Bw + (size_t)(n0 + arow) * K + achunk * 8;
  const u16* gB2 = Bw + (size_t)(n0 + 1024 + arow) * K + achunk * 8;
  u16* lA  = sA  + t * 8;
  u16* lB1 = sB1 + t * 8;
  u16* lB2 = sB2 + t * 8;

  f32x4 acc1[4][2], acc2[4][2];
#pragma unroll
  for (int i = 0; i < 4; i++) {
    acc1[i][0] = zero4(); acc1[i][1] = zero4();
    acc2[i][0] = zero4(); acc2[i][1] = zero4();
  }

  for (int kb = 0; kb < K; kb += 32) {
    async_copy16(gA + kb,                 lA);
    async_copy16(gA + kb + (size_t)64*K,  lA + 2048);
    async_copy16(gB1 + kb,                lB1);
    async_copy16(gB2 + kb,                lB2);
    __syncthreads();

    bf16x8 af[4], b1f[2], b2f[2];
#pragma unroll
    for (int mi = 0; mi < 4; mi++)
      af[mi] = *(const bf16x8*)(sA + (wm*64 + mi*16 + l16)*32 + quad*8);
#pragma unroll
    for (int ni = 0; ni < 2; ni++) {
      b1f[ni] = *(const bf16x8*)(sB1 + (wn*32 + ni*16 + l16)*32 + quad*8);
      b2f[ni] = *(const bf16x8*)(sB2 + (wn*32 + ni*16 + l16)*32 + quad*8);
    }
#pragma unroll
    for (int mi = 0; mi < 4; mi++)
#pragma unroll
      for (int ni = 0; ni < 2; ni++) {
        acc1[mi][ni] = __builtin_amdgcn_mfma_f32_16x16x32_bf16(af[mi], b1f[ni], acc1[mi][ni], 0, 0, 0);
        acc2[mi][ni] = __builtin_amdgcn_mfma_f32_16x16x32_bf16(af[mi], b2f[ni], acc2[mi][ni], 0, 0, 0);
      }
    __syncthreads();
  }

#pragma unroll
  for (int mi = 0; mi < 4; mi++) {
#pragma unroll
    for (int ni = 0; ni < 2; ni++) {
#pragma unroll
      for (int r = 0; r < 4; r++) {
        const int row = m0 + wm*64 + mi*16 + quad*4 + r;
        const int col = n0 + wn*32 + ni*16 + l16;
        hid[(size_t)row * 1024 + col] = f2b(silu(acc1[mi][ni][r]) * acc2[mi][ni][r]);
      }
    }
  }
}

// ---------- V transpose: qkv v-part [b,s,h,dh] -> vt[b,h,dh,s] ----------
__global__ __launch_bounds__(256) void vtrans_kernel(
    const u16* __restrict__ qkv, u16* __restrict__ vt)
{
  __shared__ u16 tile[64][72];
  const int st = blockIdx.x, bh = blockIdx.y;
  const int b = bh >> 4, h = bh & 15;
  const int t = threadIdx.x;
#pragma unroll
  for (int i = 0; i < 2; i++) {
    const int c = i * 256 + t;
    const int row = c >> 3, cc = c & 7;
    uint4 v = *(const uint4*)(qkv + (size_t)(b*2048 + st*64 + row)*3072 + 2048 + h*64 + cc*8);
    *(uint4*)(&tile[row][cc*8]) = v;
  }
  __syncthreads();
#pragma unroll
  for (int i = 0; i < 2; i++) {
    const int c = i * 256 + t;
    const int dh = c >> 3, cc = c & 7;
    u16 tmp[8];
#pragma unroll
    for (int j = 0; j < 8; j++) tmp[j] = tile[cc*8 + j][dh];
    *(uint4*)(vt + ((size_t)bh*64 + dh)*2048 + st*64 + cc*8) = *(uint4*)tmp;
  }
}

// ---------- fused attention (silu scores, causal) + epilogue *u ----------
__global__ __launch_bounds__(1024) void attn_kernel(
    const u16* __restrict__ qkv,       // [B*S, 3072]
    const u16* __restrict__ vt,        // [B*H, 64, 2048]
    const float* __restrict__ p_bias,  // [H, S, S] fp32
    const u16* __restrict__ ub,        // [B*S, 1024] u = silu(xn@w_u^T)
    u16* __restrict__ am_out)          // [B*S, 1024]  attn * u
{
  constexpr int S = 2048, D3 = 3072;
  __shared__ u16 sQ [128 * 64];
  __shared__ u16 sK [128 * 64];
  __shared__ u16 sVt[ 64 * 128];
  __shared__ u16 sP [128 * 128];

  const int t    = threadIdx.x;
  const int wave = t >> 6, lane = t & 63;
  const int quad = lane >> 4, l16 = lane & 15;
  const int p  = blockIdx.x & 7, bh = blockIdx.x >> 3;
  const int b  = bh >> 4, h = bh & 15;
  const int wsq = wave & 3, wsk = wave >> 2;
  const int wpq = wave & 3, wpd = wave >> 2;
  const float scale = 0.125f;

  const int srow8 = lane >> 3, sc8 = lane & 7;
  const int srow16 = lane >> 4, sc16 = lane & 15;

#pragma unroll 1
  for (int sel = 0; sel < 2; sel++) {
    const int qt = sel ? 15 - p : p;
    const int q0 = qt * 128;

    __syncthreads();
    {
      const int row = wave * 8 + srow8;
      const int gc  = sc8 ^ (row & 7);
      async_copy16(qkv + (size_t)(b*S + q0 + row)*D3 + h*64 + gc*8,
                   sQ + wave*512 + lane*8);
    }

    f32x4 oacc[2];
    oacc[0] = zero4(); oacc[1] = zero4();

    for (int kt = 0; kt <= qt; kt++) {
      const int k0 = kt * 128;
      __syncthreads();
      {
        const int row = wave * 8 + srow8;
        const int gc  = sc8 ^ (row & 7);
        async_copy16(qkv + (size_t)(b*S + k0 + row)*D3 + 1024 + h*64 + gc*8,
                     sK + wave*512 + lane*8);
        const int vrow = wave * 4 + srow16;
        const int vgc  = sc16 ^ (vrow & 15);
        async_copy16(vt + ((size_t)bh*64 + vrow)*2048 + k0 + vgc*8,
                     sVt + wave*512 + lane*8);
      }
      __syncthreads();

      float bias[2][2][4];
#pragma unroll
      for (int mi = 0; mi < 2; mi++)
#pragma unroll
        for (int ni = 0; ni < 2; ni++)
#pragma unroll
          for (int r = 0; r < 4; r++) {
            const int q = wsq*32 + mi*16 + quad*4 + r;
            const int k = wsk*32 + ni*16 + l16;
            bias[mi][ni][r] = p_bias[((size_t)h*S + q0 + q)*S + k0 + k];
          }

      bf16x8 aq[2][2], bk[2][2];
#pragma unroll
      for (int mi = 0; mi < 2; mi++)
#pragma unroll
        for (int kk = 0; kk < 2; kk++) {
          const int row = wsq*32 + mi*16 + l16;
          const int phys = (quad + kk*4) ^ (row & 7);
          aq[mi][kk] = *(const bf16x8*)(sQ + row*64 + phys*8);
        }
#pragma unroll
      for (int ni = 0; ni < 2; ni++)
#pragma unroll
        for (int kk = 0; kk < 2; kk++) {
          const int row = wsk*32 + ni*16 + l16;
          const int phys = (quad + kk*4) ^ (row & 7);
          bk[ni][kk] = *(const bf16x8*)(sK + row*64 + phys*8);
        }

      f32x4 sacc[2][2];
#pragma unroll
      for (int mi = 0; mi < 2; mi++)
#pragma unroll
        for (int ni = 0; ni < 2; ni++) {
          f32x4 s = zero4();
          s = __builtin_amdgcn_mfma_f32_16x16x32_bf16(aq[mi][0], bk[ni][0], s, 0, 0, 0);
          s = __builtin_amdgcn_mfma_f32_16x16x32_bf16(aq[mi][1], bk[ni][1], s, 0, 0, 0);
          sacc[mi][ni] = s;
        }

#pragma unroll
      for (int mi = 0; mi < 2; mi++)
#pragma unroll
        for (int ni = 0; ni < 2; ni++)
#pragma unroll
          for (int r = 0; r < 4; r++) {
            const int q = wsq*32 + mi*16 + quad*4 + r;
            const int k = wsk*32 + ni*16 + l16;
            const int qi = q0 + q, ki = k0 + k;
            float vv = sacc[mi][ni][r] * scale + bias[mi][ni][r];
            vv = (ki <= qi) ? silu(vv) : 0.f;
            const int pc = (k >> 3) ^ (q & 15);
            sP[q*128 + pc*8 + (k & 7)] = f2b(vv);
          }
      __syncthreads();

#pragma unroll
      for (int kk = 0; kk < 4; kk++) {
        bf16x8 ap[2], bv;
#pragma unroll
        for (int mi = 0; mi < 2; mi++) {
          const int row = wpq*32 + mi*16 + l16;
          const int phys = (quad + kk*4) ^ (row & 15);
          ap[mi] = *(const bf16x8*)(sP + row*128 + phys*8);
        }
        {
          const int row = wpd*16 + l16;
          const int phys = (quad + kk*4) ^ (row & 15);
          bv = *(const bf16x8*)(sVt + row*128 + phys*8);
        }
#pragma unroll
        for (int mi = 0; mi < 2; mi++)
          oacc[mi] = __builtin_amdgcn_mfma_f32_16x16x32_bf16(ap[mi], bv, oacc[mi], 0, 0, 0);
      }
    }

    // write O tile for this qt, fused with * u
#pragma unroll
    for (int mi = 0; mi < 2; mi++)
#pragma unroll
      for (int r = 0; r < 4; r++) {
        const int q  = wpq*32 + mi*16 + quad*4 + r;
        const int dh = wpd*16 + l16;
        const size_t oidx = (size_t)(b*S + q0 + q)*1024 + h*64 + dh;
        am_out[oidx] = f2b(oacc[mi][r] * b2f(ub[oidx]));
      }
  }
}

// ---------- RMSNorm ----------
__global__ __launch_bounds__(256) void rmsnorm_kernel(
    const float* __restrict__ x, const float* __restrict__ g, u16* __restrict__ out)
{
  const int row = blockIdx.x, t = threadIdx.x;
  const int wave = t >> 6, lane = t & 63;
  const size_t base = (size_t)row * 1024;
  float v[4];
#pragma unroll
  for (int i = 0; i < 4; i++) v[i] = x[base + i * 256 + t];
  float ss = v[0]*v[0] + v[1]*v[1] + v[2]*v[2] + v[3]*v[3];
#pragma unroll
  for (int off = 32; off; off >>= 1) ss += __shfl_down(ss, off);
  __shared__ float red[4];
  if (lane == 0) red[wave] = ss;
  __syncthreads();
  const float r = rsqrtf((red[0] + red[1] + red[2] + red[3]) * (1.f / 1024.f) + 1e-8f);
#pragma unroll
  for (int i = 0; i < 4; i++) {
    const int j = i * 256 + t;
    out[base + j] = f2b(g[j] * v[i] * r);
  }
}

// ---------- launch ----------
extern "C" void kernel_launch(void* const* d_in, const int* in_sizes, int n_in,
                              void* d_out, int out_size, void* d_ws, size_t ws_size,
                              hipStream_t stream)
{
  const float* x      = (const float*)d_in[0];
  const float* pbias  = (const float*)d_in[1];
  const float* w_qkv  = (const float*)d_in[3];
  const float* w_u    = (const float*)d_in[4];
  const float* g_ams  = (const float*)d_in[5];
  const float* w0     = (const float*)d_in[6];
  const float* w1     = (const float*)d_in[7];
  const float* w3     = (const float*)d_in[8];
  const float* g_mffn = (const float*)d_in[9];

  constexpr int M = 4096, D = 1024;
  char* ws = (char*)d_ws;
  u16*   xn    = (u16*)ws;                   // 8 MB
  u16*   qkv   = (u16*)(ws + (8u  << 20));   // 24 MB
  u16*   ubuf  = (u16*)(ws + (32u << 20));   // 8 MB  (u, later on)
  u16*   am    = (u16*)(ws + (40u << 20));   // 8 MB  (attn*u, later hidden)
  float* obuf  = (float*)(ws + (48u << 20)); // 16 MB fp32 residual (vt before o)
  u16*   vt    = (u16*)(ws + (48u << 20));   // 8 MB V^T, dead before obuf written
  u16*   bqkv  = (u16*)(ws + (64u << 20));   // 6 MB bf16 weights
  u16*   bu    = (u16*)(ws + (70u << 20));   // 2 MB
  u16*   b0    = (u16*)(ws + (72u << 20));   // 2 MB
  u16*   b1    = (u16*)(ws + (74u << 20));   // 4 MB
  u16*   b3    = (u16*)(ws + (78u << 20));   // 2 MB -> 80 MB total

  cvt_kernel<<<8192, 256, 0, stream>>>(w_qkv, w_u, w0, w1, w3, bqkv, bu, b0, b1, b3);
  rmsnorm_kernel<<<M, 256, 0, stream>>>(x, g_ams, xn);
  gemm_bt<0><<<dim3(24, 32), 256, 0, stream>>>(xn, bqkv, nullptr, qkv, M, 3072, D);
  gemm64_bt<1><<<dim3(16, 32), 256, 0, stream>>>(xn, bu, nullptr, ubuf, M, D, D);
  vtrans_kernel<<<dim3(32, 32), 256, 0, stream>>>(qkv, vt);
  attn_kernel<<<256, 1024, 0, stream>>>(qkv, vt, pbias, ubuf, am);
  gemm64_bt<2><<<dim3(16, 32), 256, 0, stream>>>(am, b0, x, obuf, M, D, D);
  rmsnorm_kernel<<<M, 256, 0, stream>>>(obuf, g_mffn, ubuf);
  gemm_glu<<<dim3(16, 32), 256, 0, stream>>>(ubuf, b1, am, D);
  gemm64_bt<3><<<dim3(16, 32), 256, 0, stream>>>(am, b3, obuf, (float*)d_out, M, D, D);
}